// Round 10
// baseline (230.700 us; speedup 1.0000x reference)
//
#include <hip/hip_runtime.h>

// VectorQuantizer: latents (16,128,64,64) f32, codebook (1024,128) f32.
// out[b,d,h,w] = codebook[argmin_k fl(fl(x2 - 2*dot(x,e_k)) + e2_k)][d]
//
// SINGLE-SWEEP MFMA bf16 scoring + exact fp32 rescue, round 10.
// R9 validated the algorithm (one sweep + superset collect + exact refilter)
// but its per-element shared-smin LDS read serialized the loop (main 123us,
// conflicts +1.4M). R10 keeps the structure with a PURE-REGISTER criterion:
//  pre-pass: group 0 (64 codes) MFMA + quad-shfl + cross-wave reduce ->
//            min64[px] exact; crit[i] = min64 + 2Mmax (registers).
//  sweep:    groups 1..15; per elem: emit if s <= crit; crit = fminf(crit,
//            s + 2Mmax). No LDS in loop. Superset proof: crit is always
//            min64+2Mmax or s_prev+2Mmax, both >= exact_min + 2M[px]
//            (min64 >= exact_min, s_prev >= exact_min, 2Mmax >= 2M[px]).
//            The global min beats crit strictly -> always collected.
//  exact:    sminArr seeded enc(min64); atomic-min scan over cand entries
//            (global min guaranteed present) -> exact bf16 min -> encThr =
//            enc(min + 2*(2e-4*sqrt(x2)+2.5e-4)) (slop validated R3-R9).
//  replay:   group 0 emitted vs encThr (pre-pass could not collect).
//  overflow: ncand>CAP -> reset + full exact replay (encThr >= exact thr
//            even with dropped entries: sminArr >= exact min always).
//  rescue:   exact refilter (eu<=encThr) + exact fp32 serial ascending-d
//            fmaf chain from xl; lex (t3,k) u64 atomicMin = np tie-break.
//  bfminw is DEDICATED (1KB) -- R8's aliasing onto cand was a live-range
//  collision with the post-sweep reduce.

typedef __attribute__((ext_vector_type(8))) short short8;
typedef __attribute__((ext_vector_type(4))) float f32x4;

#define VQ_D 128
#define VQ_K 1024
#define VQ_HW 4096
#define CAND_CAP 2048

__device__ inline unsigned short f2bf(float f) {   // RNE fp32->bf16
    unsigned u = __float_as_uint(f);
    return (unsigned short)((u + 0x7FFFu + ((u >> 16) & 1u)) >> 16);
}
__device__ inline unsigned f2ord(float f) {        // order-preserving encode
    const unsigned u = __float_as_uint(f);
    return u ^ (0x80000000u | (unsigned)((int)u >> 31));
}
__device__ inline float ord2f(unsigned e) {        // exact inverse
    const unsigned u = (e & 0x80000000u) ? (e ^ 0x80000000u) : ~e;
    return __uint_as_float(u);
}

__global__ __launch_bounds__(256)
void vq_prep_kernel(const float* __restrict__ cb, unsigned short* __restrict__ cbbf,
                    float* __restrict__ e2) {
    __shared__ __align__(16) float rows[32][132];
    const int tid = threadIdx.x;
    const int k0  = blockIdx.x << 5;                 // 32 codes/block, grid=32
    const float4* s4 = (const float4*)(cb + (size_t)k0 * VQ_D);
    ushort4* d4 = (ushort4*)(cbbf + (size_t)k0 * VQ_D);
    #pragma unroll
    for (int i = 0; i < 4; ++i) {                    // 1024 float4 per block
        const int idx = i * 256 + tid;               // coalesced
        const float4 v = s4[idx];
        const int r  = idx >> 5;
        const int c4 = (idx & 31) << 2;
        *(float4*)(&rows[r][c4]) = v;
        ushort4 p;
        p.x = f2bf(v.x); p.y = f2bf(v.y); p.z = f2bf(v.z); p.w = f2bf(v.w);
        d4[idx] = p;
    }
    __syncthreads();
    if (tid < 32) {                                  // serial chain, same order
        float s = 0.f;
        #pragma unroll
        for (int d = 0; d < VQ_D; ++d) {
            const float v = rows[tid][d];
            s = fmaf(v, v, s);
        }
        e2[k0 + tid] = s;
    }
}

#define VQ_MFMA(Bv)                                                              \
    f32x4 Cm[4] = {{0.f,0.f,0.f,0.f},{0.f,0.f,0.f,0.f},                          \
                   {0.f,0.f,0.f,0.f},{0.f,0.f,0.f,0.f}};                         \
    _Pragma("unroll")                                                            \
    for (int t = 0; t < 4; ++t)                                                  \
        _Pragma("unroll")                                                        \
        for (int p = 0; p < 4; ++p)                                              \
            Cm[p] = __builtin_amdgcn_mfma_f32_16x16x32_bf16(                     \
                        A[p * 4 + t], Bv[t], Cm[p], 0, 0, 0);

#define VQ_LDB(c_)                                                               \
    short8 B[4];                                                                 \
    _Pragma("unroll")                                                            \
    for (int t = 0; t < 4; ++t)                                                  \
        B[t] = *(const short8*)(bbase + (size_t)(c_) * 16 * VQ_D + t * 32);

// exact-threshold emit for one code group (iter-0 replay + overflow fallback)
#define VQ_EMIT_EXACT(c_)                                                        \
    {                                                                            \
        VQ_LDB(c_)                                                               \
        const float e2c = e2g[(c_) * 16];                                        \
        VQ_MFMA(B)                                                               \
        _Pragma("unroll")                                                        \
        for (int p = 0; p < 4; ++p)                                              \
            _Pragma("unroll")                                                    \
            for (int r = 0; r < 4; ++r) {                                        \
                const float s = fmaf(-2.0f, Cm[p][r], e2c);                      \
                const int px = p * 16 + quad * 4 + r;                            \
                const unsigned eu = f2ord(s);                                    \
                if (eu <= encThr[px]) {                                          \
                    const int idx = atomicAdd(&ncand, 1);                        \
                    if (idx < CAND_CAP)                                          \
                        cand[idx] = ((unsigned long long)eu << 32) |             \
                                    (unsigned)(px << 10) |                       \
                                    (unsigned)(wave * 256 + (c_) * 16 + mm);     \
                }                                                                \
            }                                                                    \
    }

__global__ __launch_bounds__(256)
void vq_main_kernel(const float* __restrict__ latents,
                    const float* __restrict__ cb,
                    const unsigned short* __restrict__ cbbf,
                    const float* __restrict__ e2,
                    float* __restrict__ out) {
    __shared__ __align__(16) float xl[VQ_D * 64];            // [d][px] 32 KB
    __shared__ __align__(16) unsigned short xbf[64 * 128];   // 16 KB, dies at A-build
    __shared__ float x2s[64];
    __shared__ float bfminw[4][64];                          // dedicated 1 KB
    __shared__ float seedThrS[64];
    __shared__ unsigned sminArr[64];
    __shared__ unsigned encThr[64];
    __shared__ unsigned long long fkey[64];
    __shared__ float twoMbS;
    __shared__ int ncand;
    unsigned long long* cand = (unsigned long long*)xbf;     // [2048] u64, 16 KB

    const int tid  = threadIdx.x;
    const int lane = tid & 63;
    const int wave = __builtin_amdgcn_readfirstlane(tid >> 6);
    const int quad = lane >> 4;
    const int mm   = lane & 15;
    const int blk  = blockIdx.x;
    const int b    = blk >> 6;
    const int hw0  = (blk & 63) << 6;

    const float* xg = latents + (size_t)b * VQ_D * VQ_HW + hw0;

    // ---- stage: fp32 xl[d][px] + swizzled bf16 xbf[px][d] ----
    {
        const int px4 = (tid & 15) << 2;
        const int db  = (tid >> 4) << 3;
        #pragma unroll
        for (int dp = 0; dp < 4; ++dp) {
            const int d0 = db + dp * 2;
            const float4 va = *(const float4*)(xg + (size_t)d0 * VQ_HW + px4);
            const float4 vb = *(const float4*)(xg + (size_t)(d0 + 1) * VQ_HW + px4);
            *(float4*)(xl + d0 * 64 + px4)       = va;
            *(float4*)(xl + (d0 + 1) * 64 + px4) = vb;
            const float* fa = (const float*)&va;
            const float* fb = (const float*)&vb;
            #pragma unroll
            for (int i = 0; i < 4; ++i) {
                const int px = px4 + i;
                const unsigned lo = f2bf(fa[i]);
                const unsigned hi = f2bf(fb[i]);
                const int slot = (d0 >> 3) ^ (px & 15);
                *(unsigned*)((char*)xbf + px * 256 + slot * 16 + (d0 & 7) * 2) =
                    lo | (hi << 16);
            }
        }
    }
    if (tid == 0) ncand = 0;
    if (tid < 64) fkey[tid] = ~0ULL;
    __syncthreads();   // xl + xbf staged

    // ---- A fragments (64 VGPR), conflict-free swizzled reads ----
    short8 A[16];
    #pragma unroll
    for (int p = 0; p < 4; ++p) {
        const int px = p * 16 + mm;
        #pragma unroll
        for (int t = 0; t < 4; ++t) {
            const int slot = (t * 4 + quad) ^ mm;
            A[p * 4 + t] = *(const short8*)((const char*)xbf + px * 256 + slot * 16);
        }
    }

    // x2 (exact serial chain) + block x2-max -> 2*Mmax (wave 0)
    if (tid < 64) {
        float s = 0.f;
        #pragma unroll
        for (int d = 0; d < VQ_D; ++d) {
            const float v = xl[d * 64 + tid];
            s = fmaf(v, v, s);
        }
        x2s[tid] = s;
        float mx = s;
        #pragma unroll
        for (int off = 1; off < 64; off <<= 1)
            mx = fmaxf(mx, __shfl_xor(mx, off));
        if (tid == 0) twoMbS = 2.0f * (2.0e-4f * sqrtf(mx) + 2.5e-4f);
    }
    __syncthreads();   // xbf DEAD (A in regs); x2/twoMb ready

    const float twoMb = twoMbS;
    const float* e2g = e2 + wave * 256 + mm;
    const unsigned short* bbase = cbbf + (size_t)(wave * 256 + mm) * VQ_D + quad * 8;

    // ---- pre-pass: group 0 -> exact min64[px] seeds the criterion ----
    {
        VQ_LDB(0)
        const float e2c = e2g[0];
        VQ_MFMA(B)
        float sv[16];
        #pragma unroll
        for (int p = 0; p < 4; ++p)
            #pragma unroll
            for (int r = 0; r < 4; ++r)
                sv[p * 4 + r] = fmaf(-2.0f, Cm[p][r], e2c);
        #pragma unroll
        for (int i = 0; i < 16; ++i) {
            float v = sv[i];
            v = fminf(v, __shfl_xor(v, 1));
            v = fminf(v, __shfl_xor(v, 2));
            v = fminf(v, __shfl_xor(v, 4));
            v = fminf(v, __shfl_xor(v, 8));
            sv[i] = v;
        }
        if (mm == 0) {
            #pragma unroll
            for (int p = 0; p < 4; ++p)
                #pragma unroll
                for (int r = 0; r < 4; ++r)
                    bfminw[wave][p * 16 + quad * 4 + r] = sv[p * 4 + r];
        }
    }
    __syncthreads();
    if (tid < 64) {
        const float mn = fminf(fminf(bfminw[0][tid], bfminw[1][tid]),
                               fminf(bfminw[2][tid], bfminw[3][tid]));
        seedThrS[tid] = mn + twoMb;
        sminArr[tid]  = f2ord(mn);                   // exact enc(min64)
    }
    __syncthreads();

    float crit[16];
    #pragma unroll
    for (int p = 0; p < 4; ++p)
        #pragma unroll
        for (int r = 0; r < 4; ++r)
            crit[p * 4 + r] = seedThrS[p * 16 + quad * 4 + r];

    // ---- THE sweep (groups 1..15): pure-register criterion ----
    {
        float e2n = e2g[16];
        #pragma unroll 1
        for (int cc = 1; cc < 16; ++cc) {
            VQ_LDB(cc)
            const float e2c = e2n;
            if (cc < 15) e2n = e2g[(cc + 1) * 16];
            VQ_MFMA(B)
            #pragma unroll
            for (int p = 0; p < 4; ++p)
                #pragma unroll
                for (int r = 0; r < 4; ++r) {
                    const int i = p * 4 + r;
                    const float s = fmaf(-2.0f, Cm[p][r], e2c);
                    if (s <= crit[i]) {
                        const int px = p * 16 + quad * 4 + r;
                        const int idx = atomicAdd(&ncand, 1);
                        if (idx < CAND_CAP)
                            cand[idx] =
                                ((unsigned long long)f2ord(s) << 32) |
                                (unsigned)(px << 10) |
                                (unsigned)(wave * 256 + cc * 16 + mm);
                    }
                    crit[i] = fminf(crit[i], s + twoMb);
                }
        }
    }
    __syncthreads();

    // ---- exact min from candidates (global min is guaranteed collected) ----
    int ncv = ncand;
    {
        const int n1 = ncv < CAND_CAP ? ncv : CAND_CAP;
        for (int i = tid; i < n1; i += 256) {
            const unsigned long long e = cand[i];
            atomicMin(&sminArr[(unsigned)(e >> 10) & 63u],
                      (unsigned)(e >> 32));
        }
    }
    __syncthreads();
    if (tid < 64) {
        const float mn = ord2f(sminArr[tid]);
        const float M  = 2.0e-4f * sqrtf(x2s[tid]) + 2.5e-4f;
        encThr[tid] = f2ord(mn + 2.0f * M);
    }
    __syncthreads();

    // group-0 backlog: exact-threshold replay
    VQ_EMIT_EXACT(0)
    __syncthreads();
    ncv = ncand;
    __syncthreads();
    if (ncv > CAND_CAP) {                            // overflow insurance
        if (tid == 0) ncand = 0;
        __syncthreads();
        #pragma unroll 1
        for (int cc = 0; cc < 16; ++cc) VQ_EMIT_EXACT(cc)
        __syncthreads();
        ncv = ncand;
    }
    const int nc = ncv < CAND_CAP ? ncv : CAND_CAP;

    // ---- rescue: exact refilter + exact fp32 serial chain from xl ----
    for (int i = tid; i < nc; i += 256) {
        const unsigned long long e = cand[i];
        const unsigned eu = (unsigned)(e >> 32);
        const unsigned lo = (unsigned)e;
        const int px = (int)((lo >> 10) & 63);
        if (eu > encThr[px]) continue;               // exact threshold
        const int k  = (int)(lo & 1023);
        const float* crow = cb + (size_t)k * VQ_D;
        float dot = 0.f;
        #pragma unroll
        for (int q = 0; q < 32; ++q) {
            const float4 cv = *(const float4*)(crow + q * 4);
            dot = fmaf(xl[(q * 4 + 0) * 64 + px], cv.x, dot);
            dot = fmaf(xl[(q * 4 + 1) * 64 + px], cv.y, dot);
            dot = fmaf(xl[(q * 4 + 2) * 64 + px], cv.z, dot);
            dot = fmaf(xl[(q * 4 + 3) * 64 + px], cv.w, dot);
        }
        const float t3 = (x2s[px] - 2.0f * dot) + e2[k];
        const unsigned long long key =
            ((unsigned long long)__float_as_uint(t3) << 32) | (unsigned)k;
        atomicMin(&fkey[px], key);
    }
    __syncthreads();

    // ---- writeback: f32x4 nt stores, rows direct from L2-hot cb ----
    {
        const int px4 = (tid & 15) << 2;
        const int dbl = tid >> 4;                    // 0..15
        const float* r0 = cb + (size_t)(unsigned)(fkey[px4 + 0] & 0xFFFFFFFFULL) * VQ_D;
        const float* r1 = cb + (size_t)(unsigned)(fkey[px4 + 1] & 0xFFFFFFFFULL) * VQ_D;
        const float* r2 = cb + (size_t)(unsigned)(fkey[px4 + 2] & 0xFFFFFFFFULL) * VQ_D;
        const float* r3 = cb + (size_t)(unsigned)(fkey[px4 + 3] & 0xFFFFFFFFULL) * VQ_D;
        float* og = out + (size_t)b * VQ_D * VQ_HW + hw0;
        #pragma unroll
        for (int j = 0; j < 8; ++j) {
            const int d = dbl + (j << 4);
            f32x4 v;
            v.x = r0[d]; v.y = r1[d]; v.z = r2[d]; v.w = r3[d];
            __builtin_nontemporal_store(v, (f32x4*)(og + (size_t)d * VQ_HW + px4));
        }
    }
}

extern "C" void kernel_launch(void* const* d_in, const int* in_sizes, int n_in,
                              void* d_out, int out_size, void* d_ws, size_t ws_size,
                              hipStream_t stream) {
    const float* latents = (const float*)d_in[0];
    const float* cb      = (const float*)d_in[1];
    unsigned short* cbbf = (unsigned short*)d_ws;              // 256 KB
    float* e2            = (float*)((char*)d_ws + 262144);     // 4 KB
    float* out           = (float*)d_out;

    vq_prep_kernel<<<dim3(32), dim3(256), 0, stream>>>(cb, cbbf, e2);
    vq_main_kernel<<<dim3(1024), dim3(256), 0, stream>>>(latents, cb, cbbf, e2, out);
}